// Round 5
// baseline (7731.835 us; speedup 1.0000x reference)
//
#include <hip/hip_runtime.h>
#include <hip/hip_fp16.h>

#define TLEN 16384
#define HD 128
#define L2E 1.4426950408889634f

typedef _Float16 v8h __attribute__((ext_vector_type(8)));
typedef float    v4f __attribute__((ext_vector_type(4)));

union U4H8 { uint4 u; v8h h; };

// scaled f32->f16 fragment converters (scale folded at build time, free)
__device__ __forceinline__ v8h cvt8s(const float* p, float sc) {
    v8h r;
    #pragma unroll
    for (int i = 0; i < 8; ++i) r[i] = (_Float16)(p[i] * sc);
    return r;
}
__device__ __forceinline__ v8h cvt8sums(const float* p, const float* q, float sc) {
    v8h r;
    #pragma unroll
    for (int i = 0; i < 8; ++i) r[i] = (_Float16)((p[i] + q[i]) * sc);
    return r;
}
__device__ __forceinline__ unsigned int packh2(float a, float b) {
    union { _Float16 h[2]; unsigned int u; } c;
    c.h[0] = (_Float16)a; c.h[1] = (_Float16)b; return c.u;
}
// compile-time-indexed component select (runtime g, no dynamic extract)
__device__ __forceinline__ float selg(v4f a, int g) {
    const float lo = (g & 1) ? a.y : a.x;
    const float hi = (g & 1) ? a.w : a.z;
    return (g & 2) ? hi : lo;
}
// native transcendentals: v_exp_f32 is exp2; v_rcp_f32 ~1ulp.
__device__ __forceinline__ float fexp2(float x) {
    float r; asm("v_exp_f32 %0, %1" : "=v"(r) : "v"(x)); return r;
}
__device__ __forceinline__ float frcp(float x) {
    float r; asm("v_rcp_f32 %0, %1" : "=v"(r) : "v"(x)); return r;
}
// pin a fragment into the AGPR half of the unified file (remat-proof; keeps
// arch-VGPR side under the 2-waves/SIMD budget).
#define PINA(x) asm volatile("" : "+a"(x))

// Raw workgroup barrier: LDS visibility only (lgkmcnt). No vmcnt drain, so
// global loads/stores stay in flight across steps (the chunk-pipeline's
// prefetch loads ride across ~64 step barriers).
#define BAR() asm volatile("s_waitcnt lgkmcnt(0)\n\ts_barrier" ::: "memory")

// 4-deep K accumulation chain over one 16-row tile (K=128)
__device__ __forceinline__ v4f ch4(v8h a0, v8h a1, v8h a2, v8h a3,
                                   v8h B0, v8h B1, v8h B2, v8h B3, v4f c) {
    c = __builtin_amdgcn_mfma_f32_16x16x32_f16(a0, B0, c, 0, 0, 0);
    c = __builtin_amdgcn_mfma_f32_16x16x32_f16(a1, B1, c, 0, 0, 0);
    c = __builtin_amdgcn_mfma_f32_16x16x32_f16(a2, B2, c, 0, 0, 0);
    return __builtin_amdgcn_mfma_f32_16x16x32_f16(a3, B3, c, 0, 0, 0);
}
// GRU epilogue on PRE-SCALED preacts (r,z: -log2e; n: +2log2e)
__device__ __forceinline__ float gru_h(float sRp, float sZp, float ginp,
                                       float ghnp, float hold) {
    const float r  = frcp(1.f + fexp2(sRp));
    const float z  = frcp(1.f + fexp2(sZp));
    const float e2 = fexp2(fmaf(r, ghnp, ginp));
    const float n  = fmaf(-2.f, frcp(e2 + 1.f), 1.f);   // tanh
    return fmaf(z, hold - n, n);                        // (1-z)n + z h
}

// ---------------------------------------------------------------------------
// R17 = R16 + chunk-boundary software pipeline + aR-first MFMA order.
//  * xpadL double-buffered; next chunk's x (8 floats/thread) and step_mask
//    (4 ints/lane) global loads ISSUE at chunk top and fly across the
//    lgkm-only BARs while 64 steps execute; pack+ds_write to xpadL[nxt] and
//    the 4 ballots COMMIT after the j==0 block (vmcnt wait there only
//    drains a couple of in-flight hs stores).  Removes the serial per-chunk
//    prefetch + ballot + extra barrier of R16.
//  * aR chain issued FIRST so the r-sigmoid trans chain overlaps the
//    remaining 12 MFMAs of the step.
// All fragment layouts identical to the verified R12..R16 kernels.
// ---------------------------------------------------------------------------
__global__
__attribute__((amdgpu_flat_work_group_size(512, 512)))
void gru_kernel(
    const float* __restrict__ px,
    const float* __restrict__ py,
    const float* __restrict__ vx,
    const float* __restrict__ vy,
    const float* __restrict__ Wemb,   // [128,4]
    const float* __restrict__ bemb,   // [128]
    const float* __restrict__ Wih,    // [384,128]
    const float* __restrict__ Whh,    // [384,128]
    const float* __restrict__ bih,    // [384]
    const float* __restrict__ bhh,    // [384]
    const int*   __restrict__ step_mask, // [16384]
    const int*   __restrict__ ctxp,      // [1]
    unsigned short* __restrict__ hs)     // [4*16384*128] f16-bits staging
{
    const int tid  = threadIdx.x;       // 0..511
    const int w    = tid >> 6;          // wave 0..7 -> k-range 16w..16w+15
    const int lane = tid & 63;
    const int m    = lane & 15;         // A-frag row within 16-row tile
    const int q8   = (lane >> 4) * 8;   // A/B k-offset within 32-K frag
    const int qq4  = (lane >> 4) * 4;   // D row-block
    const int cme  = lane & 3;          // my chain (D col & B chain)
    const int gme  = (lane >> 2) & 3;   // my row-within-block (replica split)
    const int kme  = 16 * w + qq4 + gme; // my h index

    // x-prefetch thread mapping (each thread owns 2 xpad entries)
    const int pc = tid & 3;             // which array
    const int pt = tid >> 2;            // t within chunk (0..127)
    const float* pxa = (pc == 0) ? px : (pc == 1) ? py : (pc == 2) ? vx : vy;

    __shared__ alignas(16) _Float16 h2L[2][4][176];  // dbuf, 352B c-stride
    __shared__ alignas(16) uint4 xpadL[2][256][4];   // dbuf x, [x0..3,1,0,0,0]
    __shared__ float WembL[512];
    __shared__ float bembL[128];
    __shared__ alignas(16) float Wc4[384][4];
    __shared__ float bfoldL[384];                    // Wih·bemb (no bih)

    // ---- A-fragments: Whh r/z/n, Wih n, merged Ws r/z  (24 frags) ----
    v8h ahr0, ahr1, ahr2, ahr3, ahz0, ahz1, ahz2, ahz3, ahn0, ahn1, ahn2, ahn3;
    v8h ain0, ain1, ain2, ain3;
    v8h asr0, asr1, asr2, asr3, asz0, asz1, asz2, asz3;
    {
        const float sRZ = -L2E, sN = 2.f * L2E;
        const float* pr = Whh + (size_t)(      16 * w + m) * 128 + q8;
        const float* pz = Whh + (size_t)(128 + 16 * w + m) * 128 + q8;
        const float* pn = Whh + (size_t)(256 + 16 * w + m) * 128 + q8;
        const float* qr = Wih + (size_t)(      16 * w + m) * 128 + q8;
        const float* qz = Wih + (size_t)(128 + 16 * w + m) * 128 + q8;
        const float* qn = Wih + (size_t)(256 + 16 * w + m) * 128 + q8;
        ahr0 = cvt8s(pr, sRZ); ahr1 = cvt8s(pr + 32, sRZ); ahr2 = cvt8s(pr + 64, sRZ); ahr3 = cvt8s(pr + 96, sRZ);
        ahz0 = cvt8s(pz, sRZ); ahz1 = cvt8s(pz + 32, sRZ); ahz2 = cvt8s(pz + 64, sRZ); ahz3 = cvt8s(pz + 96, sRZ);
        ahn0 = cvt8s(pn, sN);  ahn1 = cvt8s(pn + 32, sN);  ahn2 = cvt8s(pn + 64, sN);  ahn3 = cvt8s(pn + 96, sN);
        ain0 = cvt8s(qn, sN);  ain1 = cvt8s(qn + 32, sN);  ain2 = cvt8s(qn + 64, sN);  ain3 = cvt8s(qn + 96, sN);
        asr0 = cvt8sums(pr, qr, sRZ);           asr1 = cvt8sums(pr + 32, qr + 32, sRZ);
        asr2 = cvt8sums(pr + 64, qr + 64, sRZ); asr3 = cvt8sums(pr + 96, qr + 96, sRZ);
        asz0 = cvt8sums(pz, qz, sRZ);           asz1 = cvt8sums(pz + 32, qz + 32, sRZ);
        asz2 = cvt8sums(pz + 64, qz + 64, sRZ); asz3 = cvt8sums(pz + 96, qz + 96, sRZ);
    }
    PINA(ahr0); PINA(ahr1); PINA(ahr2); PINA(ahr3);
    PINA(ahz0); PINA(ahz1); PINA(ahz2); PINA(ahz3);
    PINA(ahn0); PINA(ahn1); PINA(ahn2); PINA(ahn3);
    PINA(ain0); PINA(ain1); PINA(ain2); PINA(ain3);
    PINA(asr0); PINA(asr1); PINA(asr2); PINA(asr3);
    PINA(asz0); PINA(asz1); PINA(asz2); PINA(asz3);

    // ---- biases as MFMA C-initializers (rows 4q..4q+3), pre-scaled ----
    const int rB = 16 * w + qq4;
    v4f bSR, bSZ, bHN, bIN;
    #pragma unroll
    for (int j = 0; j < 4; ++j) {
        bSR[j] = -L2E * (bih[rB + j]       + bhh[rB + j]);
        bSZ[j] = -L2E * (bih[128 + rB + j] + bhh[128 + rB + j]);
        bHN[j] = 2.f * L2E * bhh[256 + rB + j];
        bIN[j] = 2.f * L2E * bih[256 + rB + j];
    }

    const int ctxm = (ctxp[0] < 1) ? 1 : ctxp[0];

    WembL[tid] = Wemb[tid];
    if (tid < 128) bembL[tid] = bemb[tid];
    // zero both h-exchange banks (bank 0 is "h_{-1}" for step 0)
    for (int i = tid; i < 2 * 4 * 176; i += 512) ((_Float16*)h2L)[i] = (_Float16)0.f;
    // chunk-0 x into xpadL[0] + chunk-0 masks
    unsigned long long mb0, mb1, mb2, mb3;
    {
        uint4 u;
        u.z = packh2(1.f, 0.f); u.w = 0u;
        u.x = packh2(pxa[pt],            pxa[TLEN + pt]);
        u.y = packh2(pxa[2 * TLEN + pt], pxa[3 * TLEN + pt]);
        xpadL[0][pt][pc] = u;
        u.x = packh2(pxa[128 + pt],            pxa[TLEN + 128 + pt]);
        u.y = packh2(pxa[2 * TLEN + 128 + pt], pxa[3 * TLEN + 128 + pt]);
        xpadL[0][pt + 128][pc] = u;
        mb0 = __ballot((lane       < ctxm) || (step_mask[lane      ] == 0));
        mb1 = __ballot((lane +  64 < ctxm) || (step_mask[lane +  64] == 0));
        mb2 = __ballot((lane + 128 < ctxm) || (step_mask[lane + 128] == 0));
        mb3 = __ballot((lane + 192 < ctxm) || (step_mask[lane + 192] == 0));
    }
    __syncthreads();
    // folded embed: Wc[g] = Wih[g]·Wemb, bfold[g] = Wih[g]·bemb  (NO bih)
    if (tid < 384) {
        const float* wr = Wih + (size_t)tid * 128;
        float c0 = 0.f, c1 = 0.f, c2 = 0.f, c3 = 0.f, cb = 0.f;
        #pragma unroll 4
        for (int j = 0; j < 128; ++j) {
            const float wv = wr[j];
            const float4 e = *(const float4*)&WembL[j * 4];
            c0 = fmaf(wv, e.x, c0); c1 = fmaf(wv, e.y, c1);
            c2 = fmaf(wv, e.z, c2); c3 = fmaf(wv, e.w, c3);
            cb = fmaf(wv, bembL[j], cb);
        }
        Wc4[tid][0] = c0; Wc4[tid][1] = c1; Wc4[tid][2] = c2; Wc4[tid][3] = c3;
        bfoldL[tid] = cb;
    }
    __syncthreads();
    // Wc A-frags (pre-scaled): k=0..3 = Wc row, k=4 = bemb-fold, rest 0
    v8h wcr = {}, wcz = {}, wcn = {};
    if (lane < 16) {
        const int r0 = 16 * w + m, r1 = 128 + r0, r2 = 256 + r0;
        wcr[0] = (_Float16)(-L2E * Wc4[r0][0]); wcr[1] = (_Float16)(-L2E * Wc4[r0][1]);
        wcr[2] = (_Float16)(-L2E * Wc4[r0][2]); wcr[3] = (_Float16)(-L2E * Wc4[r0][3]);
        wcr[4] = (_Float16)(-L2E * bfoldL[r0]);
        wcz[0] = (_Float16)(-L2E * Wc4[r1][0]); wcz[1] = (_Float16)(-L2E * Wc4[r1][1]);
        wcz[2] = (_Float16)(-L2E * Wc4[r1][2]); wcz[3] = (_Float16)(-L2E * Wc4[r1][3]);
        wcz[4] = (_Float16)(-L2E * bfoldL[r1]);
        wcn[0] = (_Float16)(2.f * L2E * Wc4[r2][0]); wcn[1] = (_Float16)(2.f * L2E * Wc4[r2][1]);
        wcn[2] = (_Float16)(2.f * L2E * Wc4[r2][2]); wcn[3] = (_Float16)(2.f * L2E * Wc4[r2][3]);
        wcn[4] = (_Float16)(2.f * L2E * bfoldL[r2]);
    }
    PINA(wcr); PINA(wcz); PINA(wcn);

    float hold1 = 0.f;                 // my (cme,kme) h state, f32

    // parity-specialized LDS pointers (even step: read bank0, write bank1)
    const uint4* rdA = (const uint4*)&h2L[0][cme][0] + (lane >> 4);
    const uint4* rdB = (const uint4*)&h2L[1][cme][0] + (lane >> 4);
    _Float16*    wrA = &h2L[1][cme][kme];
    _Float16*    wrB = &h2L[0][cme][kme];
    // per-lane hs stream pointer; 8-step immediate offsets
    unsigned short* hp = hs + (size_t)cme * (TLEN * 128) + kme;

#define STEP(RD, WR, XOFF, HOFF, UX)                                         \
    {                                                                        \
        U4H8 b0, b1, b2, b3;                                                 \
        b0.u = (RD)[0]; b1.u = (RD)[4]; b2.u = (RD)[8]; b3.u = (RD)[12];     \
        v4f aR, aZ, aNh, aNi;                                                \
        if (!(UX)) {                                                         \
            aR  = ch4(asr0, asr1, asr2, asr3, b0.h, b1.h, b2.h, b3.h, bSR);  \
            aNh = ch4(ahn0, ahn1, ahn2, ahn3, b0.h, b1.h, b2.h, b3.h, bHN);  \
            aNi = ch4(ain0, ain1, ain2, ain3, b0.h, b1.h, b2.h, b3.h, bIN);  \
            aZ  = ch4(asz0, asz1, asz2, asz3, b0.h, b1.h, b2.h, b3.h, bSZ);  \
        } else {                                                             \
            U4H8 xb; xb.u = xq[XOFF];                                        \
            aR  = ch4(ahr0, ahr1, ahr2, ahr3, b0.h, b1.h, b2.h, b3.h, bSR);  \
            aR  = __builtin_amdgcn_mfma_f32_16x16x32_f16(wcr, xb.h, aR, 0, 0, 0); \
            aNh = ch4(ahn0, ahn1, ahn2, ahn3, b0.h, b1.h, b2.h, b3.h, bHN);  \
            aNi = __builtin_amdgcn_mfma_f32_16x16x32_f16(wcn, xb.h, bIN, 0, 0, 0); \
            aZ  = ch4(ahz0, ahz1, ahz2, ahz3, b0.h, b1.h, b2.h, b3.h, bSZ);  \
            aZ  = __builtin_amdgcn_mfma_f32_16x16x32_f16(wcz, xb.h, aZ, 0, 0, 0); \
        }                                                                    \
        const float hnew = gru_h(selg(aR, gme), selg(aZ, gme),               \
                                 selg(aNi, gme), selg(aNh, gme), hold1);     \
        hold1 = hnew;                                                        \
        union { _Float16 f; unsigned short u; } hv; hv.f = (_Float16)hnew;   \
        *(WR) = hv.f;                                                        \
        hp[HOFF] = hv.u;                                                     \
        BAR();                                                               \
    }

    int cur = 0;
    for (int t0 = 0; t0 < TLEN; t0 += 256) {
        const int  t0n  = t0 + 256;
        const bool more = (t0n < TLEN);
        const int  nxt  = cur ^ 1;
        // ---- issue next-chunk global loads (fly across the step BARs) ----
        float f0 = 0.f, f1 = 0.f, f2 = 0.f, f3 = 0.f;
        float f4 = 0.f, f5 = 0.f, f6 = 0.f, f7 = 0.f;
        int   n0 = 0, n1 = 0, n2 = 0, n3 = 0;
        if (more) {
            const int g = t0n + pt;
            f0 = pxa[g];                  f1 = pxa[TLEN + g];
            f2 = pxa[2 * TLEN + g];       f3 = pxa[3 * TLEN + g];
            f4 = pxa[128 + g];            f5 = pxa[TLEN + 128 + g];
            f6 = pxa[2 * TLEN + 128 + g]; f7 = pxa[3 * TLEN + 128 + g];
            const int tb = t0n + lane;
            n0 = step_mask[tb];       n1 = step_mask[tb + 64];
            n2 = step_mask[tb + 128]; n3 = step_mask[tb + 192];
        }
        const uint4* xq = (const uint4*)&xpadL[cur][0][cme];
        unsigned long long nmb0 = 0, nmb1 = 0, nmb2 = 0, nmb3 = 0;
        #pragma unroll 1
        for (int j = 0; j < 4; ++j) {
            const unsigned long long mj =
                (j == 0) ? mb0 : (j == 1) ? mb1 : (j == 2) ? mb2 : mb3;
            #pragma unroll 1
            for (int t2 = 0; t2 < 64; t2 += 8) {
                const unsigned u0 = (unsigned)(mj >> t2);   // low 8 bits used
                STEP(rdA, wrA,  0,   0, (u0      ) & 1u);
                STEP(rdB, wrB,  4, 128, (u0 >> 1) & 1u);
                STEP(rdA, wrA,  8, 256, (u0 >> 2) & 1u);
                STEP(rdB, wrB, 12, 384, (u0 >> 3) & 1u);
                STEP(rdA, wrA, 16, 512, (u0 >> 4) & 1u);
                STEP(rdB, wrB, 20, 640, (u0 >> 5) & 1u);
                STEP(rdA, wrA, 24, 768, (u0 >> 6) & 1u);
                STEP(rdB, wrB, 28, 896, (u0 >> 7) & 1u);
                xq += 32;
                hp += 1024;
            }
            // ---- commit next-chunk x/masks after 64 steps (loads done) ----
            if (j == 0 && more) {
                uint4 u;
                u.z = packh2(1.f, 0.f); u.w = 0u;
                u.x = packh2(f0, f1);   u.y = packh2(f2, f3);
                xpadL[nxt][pt][pc] = u;
                u.x = packh2(f4, f5);   u.y = packh2(f6, f7);
                xpadL[nxt][pt + 128][pc] = u;
                const int tb = t0n + lane;
                nmb0 = __ballot((tb       < ctxm) || (n0 == 0));
                nmb1 = __ballot((tb +  64 < ctxm) || (n1 == 0));
                nmb2 = __ballot((tb + 128 < ctxm) || (n2 == 0));
                nmb3 = __ballot((tb + 192 < ctxm) || (n3 == 0));
            }
        }
        if (more) { mb0 = nmb0; mb1 = nmb1; mb2 = nmb2; mb3 = nmb3; cur = nxt; }
        // no extra barrier needed: 192 step-BARs separate the xpad[nxt]
        // writes from the next chunk's first read.
    }
#undef STEP
}

// ---------------------------------------------------------------------------
// Head MLP over all 65536 hidden states (unchanged).
// ---------------------------------------------------------------------------
__global__ __launch_bounds__(64) void head_kernel(
    const float*  __restrict__ W1,
    const float*  __restrict__ b1,
    const float*  __restrict__ W2,
    const float*  __restrict__ b2,
    const float*  __restrict__ W3,
    const float*  __restrict__ b3,
    const __half* __restrict__ hs,
    float*        __restrict__ out)
{
    __shared__ float W1L[64 * 128];
    __shared__ float W2L[64 * 64];
    __shared__ float W3L[2 * 64];
    __shared__ float b1L[64], b2L[64], b3L[2];
    __shared__ float y1L[64 * 65];

    const int tid = threadIdx.x;
    {
        float4* dst1 = (float4*)W1L; const float4* src1 = (const float4*)W1;
        for (int i = tid; i < 2048; i += 64) dst1[i] = src1[i];
        float4* dst2 = (float4*)W2L; const float4* src2 = (const float4*)W2;
        for (int i = tid; i < 1024; i += 64) dst2[i] = src2[i];
        if (tid < 32) ((float4*)W3L)[tid] = ((const float4*)W3)[tid];
        b1L[tid] = b1[tid];
        b2L[tid] = b2[tid];
        if (tid < 2) b3L[tid] = b3[tid];
    }
    __syncthreads();

    const int row = blockIdx.x * 64 + tid;
    float h[128];
    {
        const uint4* hp = (const uint4*)(hs + (size_t)row * HD);
        #pragma unroll
        for (int c = 0; c < 16; ++c) {
            uint4 q = hp[c];
            const __half2* hh = (const __half2*)&q;
            #pragma unroll
            for (int d = 0; d < 4; ++d) {
                const float2 f = __half22float2(hh[d]);
                h[c*8 + d*2 + 0] = f.x;
                h[c*8 + d*2 + 1] = f.y;
            }
        }
    }
    for (int l = 0; l < 64; ++l) {
        float a0 = b1L[l], a1 = 0.f;
        #pragma unroll
        for (int j = 0; j < 128; j += 4) {
            const float4 wv = *(const float4*)&W1L[l*128 + j];
            a0 = fmaf(wv.x, h[j+0], a0);
            a1 = fmaf(wv.y, h[j+1], a1);
            a0 = fmaf(wv.z, h[j+2], a0);
            a1 = fmaf(wv.w, h[j+3], a1);
        }
        const float acc = a0 + a1;
        y1L[tid * 65 + l] = (acc > 0.f) ? acc : (__expf(acc) - 1.f);
    }
    float y30 = b3L[0], y31 = b3L[1];
    for (int l = 0; l < 64; ++l) {
        float a0 = b2L[l], a1 = 0.f;
        const int yb = tid * 65;
        #pragma unroll
        for (int j = 0; j < 64; j += 4) {
            const float4 wv = *(const float4*)&W2L[l*64 + j];
            a0 = fmaf(wv.x, y1L[yb + j+0], a0);
            a1 = fmaf(wv.y, y1L[yb + j+1], a1);
            a0 = fmaf(wv.z, y1L[yb + j+2], a0);
            a1 = fmaf(wv.w, y1L[yb + j+3], a1);
        }
        const float acc = a0 + a1;
        const float v = (acc > 0.f) ? acc : (__expf(acc) - 1.f);
        y30 = fmaf(W3L[l],      v, y30);
        y31 = fmaf(W3L[64 + l], v, y31);
    }
    out[row]            = y30;
    out[4 * TLEN + row] = y31;
}

extern "C" void kernel_launch(void* const* d_in, const int* in_sizes, int n_in,
                              void* d_out, int out_size, void* d_ws, size_t ws_size,
                              hipStream_t stream) {
    const float* px   = (const float*)d_in[0];
    const float* py   = (const float*)d_in[1];
    const float* vx   = (const float*)d_in[2];
    const float* vy   = (const float*)d_in[3];
    const float* Wemb = (const float*)d_in[4];
    const float* bemb = (const float*)d_in[5];
    const float* Wih  = (const float*)d_in[6];
    const float* Whh  = (const float*)d_in[7];
    const float* bih  = (const float*)d_in[8];
    const float* bhh  = (const float*)d_in[9];
    const float* W1   = (const float*)d_in[10];
    const float* b1   = (const float*)d_in[11];
    const float* W2   = (const float*)d_in[12];
    const float* b2   = (const float*)d_in[13];
    const float* W3   = (const float*)d_in[14];
    const float* b3   = (const float*)d_in[15];
    const int* step_mask = (const int*)d_in[16];
    const int* ctx       = (const int*)d_in[17];
    unsigned short* hs = (unsigned short*)d_ws;  // 4*16384*128 f16-bits = 16.8 MB
    float* out = (float*)d_out;                  // f32, [2][4][16384] flat

    hipLaunchKernelGGL(gru_kernel, dim3(1), dim3(512), 0, stream,
                       px, py, vx, vy, Wemb, bemb, Wih, Whh, bih, bhh,
                       step_mask, ctx, hs);
    hipLaunchKernelGGL(head_kernel, dim3(1024), dim3(64), 0, stream,
                       W1, b1, W2, b2, W3, b3, (const __half*)hs, out);
}

// Round 6
// 7120.466 us; speedup vs baseline: 1.0859x; 1.0859x over previous
//
#include <hip/hip_runtime.h>
#include <hip/hip_fp16.h>

#define TLEN 16384
#define HD 128
#define L2E 1.4426950408889634f

typedef _Float16 v8h __attribute__((ext_vector_type(8)));
typedef float    v4f __attribute__((ext_vector_type(4)));

union U4H8 { uint4 u; v8h h; };

// scaled f32->f16 fragment converters (scale folded at build time, free)
__device__ __forceinline__ v8h cvt8s(const float* p, float sc) {
    v8h r;
    #pragma unroll
    for (int i = 0; i < 8; ++i) r[i] = (_Float16)(p[i] * sc);
    return r;
}
__device__ __forceinline__ v8h cvt8sums(const float* p, const float* q, float sc) {
    v8h r;
    #pragma unroll
    for (int i = 0; i < 8; ++i) r[i] = (_Float16)((p[i] + q[i]) * sc);
    return r;
}
__device__ __forceinline__ unsigned int packh2(float a, float b) {
    union { _Float16 h[2]; unsigned int u; } c;
    c.h[0] = (_Float16)a; c.h[1] = (_Float16)b; return c.u;
}
// compile-time-indexed component select (runtime g, no dynamic extract)
__device__ __forceinline__ float selg(v4f a, int g) {
    const float lo = (g & 1) ? a.y : a.x;
    const float hi = (g & 1) ? a.w : a.z;
    return (g & 2) ? hi : lo;
}
// native transcendentals: v_exp_f32 is exp2; v_rcp_f32 ~1ulp. Avoids the
// IEEE div_scale/div_fmas/div_fixup sequence (~10 VALU each) the compiler
// emits for 1.f/x without fast-math.
__device__ __forceinline__ float fexp2(float x) {
    float r; asm("v_exp_f32 %0, %1" : "=v"(r) : "v"(x)); return r;
}
__device__ __forceinline__ float frcp(float x) {
    float r; asm("v_rcp_f32 %0, %1" : "=v"(r) : "v"(x)); return r;
}
// pin a fragment into the AGPR half of the unified file: relieves the arch
// VGPR budget (need <=~128 arch VGPR for 2 waves/SIMD) AND is remat-proof.
#define PINA(x) asm volatile("" : "+a"(x))

// Raw workgroup barrier: LDS visibility only (lgkmcnt). No vmcnt/expcnt
// drain, so hs global stores stay in flight across steps.
#define BAR() asm volatile("s_waitcnt lgkmcnt(0)\n\ts_barrier" ::: "memory")

// 4-deep K accumulation chain over one 16-row tile (K=128)
__device__ __forceinline__ v4f ch4(v8h a0, v8h a1, v8h a2, v8h a3,
                                   v8h B0, v8h B1, v8h B2, v8h B3, v4f c) {
    c = __builtin_amdgcn_mfma_f32_16x16x32_f16(a0, B0, c, 0, 0, 0);
    c = __builtin_amdgcn_mfma_f32_16x16x32_f16(a1, B1, c, 0, 0, 0);
    c = __builtin_amdgcn_mfma_f32_16x16x32_f16(a2, B2, c, 0, 0, 0);
    return __builtin_amdgcn_mfma_f32_16x16x32_f16(a3, B3, c, 0, 0, 0);
}
// GRU epilogue on PRE-SCALED preacts:
//   sRp = -log2e * sR, sZp = -log2e * sZ, ginp/ghnp = 2*log2e * (gin/ghn)
//   sigmoid(x) = rcp(1 + exp2(-log2e x)); tanh via exp2 of the 2log2e form.
__device__ __forceinline__ float gru_h(float sRp, float sZp, float ginp,
                                       float ghnp, float hold) {
    const float r  = frcp(1.f + fexp2(sRp));
    const float z  = frcp(1.f + fexp2(sZp));
    const float e2 = fexp2(fmaf(r, ghnp, ginp));
    const float n  = fmaf(-2.f, frcp(e2 + 1.f), 1.f);   // tanh
    return fmaf(z, hold - n, n);                        // (1-z)n + z h
}

// ---------------------------------------------------------------------------
// R18 = exact revert to R16 (best verified: 6950us gru).  R17's chunk
// pipeline regressed 8%: 12 extra live VGPRs across the step loop degraded
// the schedule (the loop is register-schedule-critical).  R16 structure:
//  * 8 waves (2/SIMD), merged Ws=Wih+Whh r/z gates, split n gate.
//  * ballot-mask ux branch (SGPR resolve), lgkm-only raw barrier,
//    fire-and-forget hs stores, parity-specialized h2L double buffer.
//  * v_rcp/v_exp epilogue with log2e folded into weights at frag build.
//  * 8-step unroll with immediate LDS/global offsets.
//  * h2L c-stride 352B: b16 writes 2-way (free), b128 multicast reads 2-way.
// All fragment layouts identical to the verified R12..R16 kernels.
// ---------------------------------------------------------------------------
__global__
__attribute__((amdgpu_flat_work_group_size(512, 512)))
void gru_kernel(
    const float* __restrict__ px,
    const float* __restrict__ py,
    const float* __restrict__ vx,
    const float* __restrict__ vy,
    const float* __restrict__ Wemb,   // [128,4]
    const float* __restrict__ bemb,   // [128]
    const float* __restrict__ Wih,    // [384,128]
    const float* __restrict__ Whh,    // [384,128]
    const float* __restrict__ bih,    // [384]
    const float* __restrict__ bhh,    // [384]
    const int*   __restrict__ step_mask, // [16384]
    const int*   __restrict__ ctxp,      // [1]
    unsigned short* __restrict__ hs)     // [4*16384*128] f16-bits staging
{
    const int tid  = threadIdx.x;       // 0..511
    const int w    = tid >> 6;          // wave 0..7 -> k-range 16w..16w+15
    const int lane = tid & 63;
    const int m    = lane & 15;         // A-frag row within 16-row tile
    const int q8   = (lane >> 4) * 8;   // A/B k-offset within 32-K frag
    const int qq4  = (lane >> 4) * 4;   // D row-block
    const int cme  = lane & 3;          // my chain (D col & B chain)
    const int gme  = (lane >> 2) & 3;   // my row-within-block (replica split)
    const int kme  = 16 * w + qq4 + gme; // my h index

    __shared__ alignas(16) _Float16 h2L[2][4][176];  // dbuf, 352B c-stride
    __shared__ alignas(16) uint4 xpadL[256][4];      // [x0..x3,1,0,0,0] f16
    __shared__ float WembL[512];
    __shared__ float bembL[128];
    __shared__ alignas(16) float Wc4[384][4];
    __shared__ float bfoldL[384];                    // Wih·bemb (no bih)

    // ---- A-fragments: Whh r/z/n, Wih n, merged Ws r/z  (24 frags) ----
    // r,z scaled by -log2e; n by +2log2e (see gru_h).
    v8h ahr0, ahr1, ahr2, ahr3, ahz0, ahz1, ahz2, ahz3, ahn0, ahn1, ahn2, ahn3;
    v8h ain0, ain1, ain2, ain3;
    v8h asr0, asr1, asr2, asr3, asz0, asz1, asz2, asz3;
    {
        const float sRZ = -L2E, sN = 2.f * L2E;
        const float* pr = Whh + (size_t)(      16 * w + m) * 128 + q8;
        const float* pz = Whh + (size_t)(128 + 16 * w + m) * 128 + q8;
        const float* pn = Whh + (size_t)(256 + 16 * w + m) * 128 + q8;
        const float* qr = Wih + (size_t)(      16 * w + m) * 128 + q8;
        const float* qz = Wih + (size_t)(128 + 16 * w + m) * 128 + q8;
        const float* qn = Wih + (size_t)(256 + 16 * w + m) * 128 + q8;
        ahr0 = cvt8s(pr, sRZ); ahr1 = cvt8s(pr + 32, sRZ); ahr2 = cvt8s(pr + 64, sRZ); ahr3 = cvt8s(pr + 96, sRZ);
        ahz0 = cvt8s(pz, sRZ); ahz1 = cvt8s(pz + 32, sRZ); ahz2 = cvt8s(pz + 64, sRZ); ahz3 = cvt8s(pz + 96, sRZ);
        ahn0 = cvt8s(pn, sN);  ahn1 = cvt8s(pn + 32, sN);  ahn2 = cvt8s(pn + 64, sN);  ahn3 = cvt8s(pn + 96, sN);
        ain0 = cvt8s(qn, sN);  ain1 = cvt8s(qn + 32, sN);  ain2 = cvt8s(qn + 64, sN);  ain3 = cvt8s(qn + 96, sN);
        asr0 = cvt8sums(pr, qr, sRZ);           asr1 = cvt8sums(pr + 32, qr + 32, sRZ);
        asr2 = cvt8sums(pr + 64, qr + 64, sRZ); asr3 = cvt8sums(pr + 96, qr + 96, sRZ);
        asz0 = cvt8sums(pz, qz, sRZ);           asz1 = cvt8sums(pz + 32, qz + 32, sRZ);
        asz2 = cvt8sums(pz + 64, qz + 64, sRZ); asz3 = cvt8sums(pz + 96, qz + 96, sRZ);
    }
    PINA(ahr0); PINA(ahr1); PINA(ahr2); PINA(ahr3);
    PINA(ahz0); PINA(ahz1); PINA(ahz2); PINA(ahz3);
    PINA(ahn0); PINA(ahn1); PINA(ahn2); PINA(ahn3);
    PINA(ain0); PINA(ain1); PINA(ain2); PINA(ain3);
    PINA(asr0); PINA(asr1); PINA(asr2); PINA(asr3);
    PINA(asz0); PINA(asz1); PINA(asz2); PINA(asz3);

    // ---- biases as MFMA C-initializers (rows 4q..4q+3), pre-scaled ----
    const int rB = 16 * w + qq4;
    v4f bSR, bSZ, bHN, bIN;
    #pragma unroll
    for (int j = 0; j < 4; ++j) {
        bSR[j] = -L2E * (bih[rB + j]       + bhh[rB + j]);
        bSZ[j] = -L2E * (bih[128 + rB + j] + bhh[128 + rB + j]);
        bHN[j] = 2.f * L2E * bhh[256 + rB + j];
        bIN[j] = 2.f * L2E * bih[256 + rB + j];
    }

    WembL[tid] = Wemb[tid];
    if (tid < 128) bembL[tid] = bemb[tid];
    // zero both h-exchange banks (bank 0 is "h_{-1}" for step 0)
    for (int i = tid; i < 2 * 4 * 176; i += 512) ((_Float16*)h2L)[i] = (_Float16)0.f;
    __syncthreads();
    // folded embed: Wc[g] = Wih[g]·Wemb, bfold[g] = Wih[g]·bemb  (NO bih)
    if (tid < 384) {
        const float* wr = Wih + (size_t)tid * 128;
        float c0 = 0.f, c1 = 0.f, c2 = 0.f, c3 = 0.f, cb = 0.f;
        #pragma unroll 4
        for (int j = 0; j < 128; ++j) {
            const float wv = wr[j];
            const float4 e = *(const float4*)&WembL[j * 4];
            c0 = fmaf(wv, e.x, c0); c1 = fmaf(wv, e.y, c1);
            c2 = fmaf(wv, e.z, c2); c3 = fmaf(wv, e.w, c3);
            cb = fmaf(wv, bembL[j], cb);
        }
        Wc4[tid][0] = c0; Wc4[tid][1] = c1; Wc4[tid][2] = c2; Wc4[tid][3] = c3;
        bfoldL[tid] = cb;
    }
    __syncthreads();
    // Wc A-frags (pre-scaled): k=0..3 = Wc row, k=4 = bemb-fold, rest 0
    v8h wcr = {}, wcz = {}, wcn = {};
    if (lane < 16) {
        const int r0 = 16 * w + m, r1 = 128 + r0, r2 = 256 + r0;
        wcr[0] = (_Float16)(-L2E * Wc4[r0][0]); wcr[1] = (_Float16)(-L2E * Wc4[r0][1]);
        wcr[2] = (_Float16)(-L2E * Wc4[r0][2]); wcr[3] = (_Float16)(-L2E * Wc4[r0][3]);
        wcr[4] = (_Float16)(-L2E * bfoldL[r0]);
        wcz[0] = (_Float16)(-L2E * Wc4[r1][0]); wcz[1] = (_Float16)(-L2E * Wc4[r1][1]);
        wcz[2] = (_Float16)(-L2E * Wc4[r1][2]); wcz[3] = (_Float16)(-L2E * Wc4[r1][3]);
        wcz[4] = (_Float16)(-L2E * bfoldL[r1]);
        wcn[0] = (_Float16)(2.f * L2E * Wc4[r2][0]); wcn[1] = (_Float16)(2.f * L2E * Wc4[r2][1]);
        wcn[2] = (_Float16)(2.f * L2E * Wc4[r2][2]); wcn[3] = (_Float16)(2.f * L2E * Wc4[r2][3]);
        wcn[4] = (_Float16)(2.f * L2E * bfoldL[r2]);
    }
    PINA(wcr); PINA(wcz); PINA(wcn);

    const int ctxm = (ctxp[0] < 1) ? 1 : ctxp[0];
    float hold1 = 0.f;                 // my (cme,kme) h state, f32

    // parity-specialized LDS pointers (even step: read bank0, write bank1)
    const uint4* rdA = (const uint4*)&h2L[0][cme][0] + (lane >> 4);
    const uint4* rdB = (const uint4*)&h2L[1][cme][0] + (lane >> 4);
    _Float16*    wrA = &h2L[1][cme][kme];
    _Float16*    wrB = &h2L[0][cme][kme];
    // per-lane hs stream pointer; advanced once per 8 steps, stores use
    // compile-time immediate offsets (128*i elements = 256*i bytes < 4096)
    unsigned short* hp = hs + (size_t)cme * (TLEN * 128) + kme;

#define STEP(RD, WR, XOFF, HOFF, UX)                                         \
    {                                                                        \
        U4H8 b0, b1, b2, b3;                                                 \
        b0.u = (RD)[0]; b1.u = (RD)[4]; b2.u = (RD)[8]; b3.u = (RD)[12];     \
        v4f aR, aZ, aNi;                                                     \
        v4f aNh = ch4(ahn0, ahn1, ahn2, ahn3, b0.h, b1.h, b2.h, b3.h, bHN);  \
        if (!(UX)) {                                                         \
            aR  = ch4(asr0, asr1, asr2, asr3, b0.h, b1.h, b2.h, b3.h, bSR);  \
            aNi = ch4(ain0, ain1, ain2, ain3, b0.h, b1.h, b2.h, b3.h, bIN);  \
            aZ  = ch4(asz0, asz1, asz2, asz3, b0.h, b1.h, b2.h, b3.h, bSZ);  \
        } else {                                                             \
            U4H8 xb; xb.u = xq[XOFF];                                        \
            aR  = ch4(ahr0, ahr1, ahr2, ahr3, b0.h, b1.h, b2.h, b3.h, bSR);  \
            aR  = __builtin_amdgcn_mfma_f32_16x16x32_f16(wcr, xb.h, aR, 0, 0, 0); \
            aNi = __builtin_amdgcn_mfma_f32_16x16x32_f16(wcn, xb.h, bIN, 0, 0, 0); \
            aZ  = ch4(ahz0, ahz1, ahz2, ahz3, b0.h, b1.h, b2.h, b3.h, bSZ);  \
            aZ  = __builtin_amdgcn_mfma_f32_16x16x32_f16(wcz, xb.h, aZ, 0, 0, 0); \
        }                                                                    \
        const float hnew = gru_h(selg(aR, gme), selg(aZ, gme),               \
                                 selg(aNi, gme), selg(aNh, gme), hold1);     \
        hold1 = hnew;                                                        \
        union { _Float16 f; unsigned short u; } hv; hv.f = (_Float16)hnew;   \
        *(WR) = hv.f;                                                        \
        hp[HOFF] = hv.u;                                                     \
        BAR();                                                               \
    }

    for (int t0 = 0; t0 < TLEN; t0 += 256) {
        // prefetch x (f16-padded with 1.0 at k=4)
        for (int i = tid; i < 1024; i += 512) {
            const int t = i >> 2, c = i & 3;
            const int gt = t0 + t;
            const float* xa = (c == 0) ? px : (c == 1) ? py : (c == 2) ? vx : vy;
            uint4 u;
            u.x = packh2(xa[gt],            xa[TLEN + gt]);
            u.y = packh2(xa[2 * TLEN + gt], xa[3 * TLEN + gt]);
            u.z = packh2(1.f, 0.f);
            u.w = 0u;
            xpadL[t][c] = u;
        }
        // use_x flags for the 256 steps as 4 wave-uniform 64-bit masks
        unsigned long long mb0, mb1, mb2, mb3;
        {
            const int tb = t0 + lane;
            mb0 = __ballot((tb       < ctxm) || (step_mask[tb      ] == 0));
            mb1 = __ballot((tb +  64 < ctxm) || (step_mask[tb +  64] == 0));
            mb2 = __ballot((tb + 128 < ctxm) || (step_mask[tb + 128] == 0));
            mb3 = __ballot((tb + 192 < ctxm) || (step_mask[tb + 192] == 0));
        }
        BAR();
        const uint4* xq = (const uint4*)&xpadL[0][cme];
        #pragma unroll 1
        for (int j = 0; j < 4; ++j) {
            const unsigned long long mj =
                (j == 0) ? mb0 : (j == 1) ? mb1 : (j == 2) ? mb2 : mb3;
            #pragma unroll 1
            for (int t2 = 0; t2 < 64; t2 += 8) {
                const unsigned u0 = (unsigned)(mj >> t2);   // low 8 bits used
                STEP(rdA, wrA,  0,   0, (u0      ) & 1u);
                STEP(rdB, wrB,  4, 128, (u0 >> 1) & 1u);
                STEP(rdA, wrA,  8, 256, (u0 >> 2) & 1u);
                STEP(rdB, wrB, 12, 384, (u0 >> 3) & 1u);
                STEP(rdA, wrA, 16, 512, (u0 >> 4) & 1u);
                STEP(rdB, wrB, 20, 640, (u0 >> 5) & 1u);
                STEP(rdA, wrA, 24, 768, (u0 >> 6) & 1u);
                STEP(rdB, wrB, 28, 896, (u0 >> 7) & 1u);
                xq += 32;
                hp += 1024;
            }
        }
    }
#undef STEP
}

// ---------------------------------------------------------------------------
// Head MLP over all 65536 hidden states (unchanged).
// ---------------------------------------------------------------------------
__global__ __launch_bounds__(64) void head_kernel(
    const float*  __restrict__ W1,
    const float*  __restrict__ b1,
    const float*  __restrict__ W2,
    const float*  __restrict__ b2,
    const float*  __restrict__ W3,
    const float*  __restrict__ b3,
    const __half* __restrict__ hs,
    float*        __restrict__ out)
{
    __shared__ float W1L[64 * 128];
    __shared__ float W2L[64 * 64];
    __shared__ float W3L[2 * 64];
    __shared__ float b1L[64], b2L[64], b3L[2];
    __shared__ float y1L[64 * 65];

    const int tid = threadIdx.x;
    {
        float4* dst1 = (float4*)W1L; const float4* src1 = (const float4*)W1;
        for (int i = tid; i < 2048; i += 64) dst1[i] = src1[i];
        float4* dst2 = (float4*)W2L; const float4* src2 = (const float4*)W2;
        for (int i = tid; i < 1024; i += 64) dst2[i] = src2[i];
        if (tid < 32) ((float4*)W3L)[tid] = ((const float4*)W3)[tid];
        b1L[tid] = b1[tid];
        b2L[tid] = b2[tid];
        if (tid < 2) b3L[tid] = b3[tid];
    }
    __syncthreads();

    const int row = blockIdx.x * 64 + tid;
    float h[128];
    {
        const uint4* hp = (const uint4*)(hs + (size_t)row * HD);
        #pragma unroll
        for (int c = 0; c < 16; ++c) {
            uint4 q = hp[c];
            const __half2* hh = (const __half2*)&q;
            #pragma unroll
            for (int d = 0; d < 4; ++d) {
                const float2 f = __half22float2(hh[d]);
                h[c*8 + d*2 + 0] = f.x;
                h[c*8 + d*2 + 1] = f.y;
            }
        }
    }
    for (int l = 0; l < 64; ++l) {
        float a0 = b1L[l], a1 = 0.f;
        #pragma unroll
        for (int j = 0; j < 128; j += 4) {
            const float4 wv = *(const float4*)&W1L[l*128 + j];
            a0 = fmaf(wv.x, h[j+0], a0);
            a1 = fmaf(wv.y, h[j+1], a1);
            a0 = fmaf(wv.z, h[j+2], a0);
            a1 = fmaf(wv.w, h[j+3], a1);
        }
        const float acc = a0 + a1;
        y1L[tid * 65 + l] = (acc > 0.f) ? acc : (__expf(acc) - 1.f);
    }
    float y30 = b3L[0], y31 = b3L[1];
    for (int l = 0; l < 64; ++l) {
        float a0 = b2L[l], a1 = 0.f;
        const int yb = tid * 65;
        #pragma unroll
        for (int j = 0; j < 64; j += 4) {
            const float4 wv = *(const float4*)&W2L[l*64 + j];
            a0 = fmaf(wv.x, y1L[yb + j+0], a0);
            a1 = fmaf(wv.y, y1L[yb + j+1], a1);
            a0 = fmaf(wv.z, y1L[yb + j+2], a0);
            a1 = fmaf(wv.w, y1L[yb + j+3], a1);
        }
        const float acc = a0 + a1;
        const float v = (acc > 0.f) ? acc : (__expf(acc) - 1.f);
        y30 = fmaf(W3L[l],      v, y30);
        y31 = fmaf(W3L[64 + l], v, y31);
    }
    out[row]            = y30;
    out[4 * TLEN + row] = y31;
}

extern "C" void kernel_launch(void* const* d_in, const int* in_sizes, int n_in,
                              void* d_out, int out_size, void* d_ws, size_t ws_size,
                              hipStream_t stream) {
    const float* px   = (const float*)d_in[0];
    const float* py   = (const float*)d_in[1];
    const float* vx   = (const float*)d_in[2];
    const float* vy   = (const float*)d_in[3];
    const float* Wemb = (const float*)d_in[4];
    const float* bemb = (const float*)d_in[5];
    const float* Wih  = (const float*)d_in[6];
    const float* Whh  = (const float*)d_in[7];
    const float* bih  = (const float*)d_in[8];
    const float* bhh  = (const float*)d_in[9];
    const float* W1   = (const float*)d_in[10];
    const float* b1   = (const float*)d_in[11];
    const float* W2   = (const float*)d_in[12];
    const float* b2   = (const float*)d_in[13];
    const float* W3   = (const float*)d_in[14];
    const float* b3   = (const float*)d_in[15];
    const int* step_mask = (const int*)d_in[16];
    const int* ctx       = (const int*)d_in[17];
    unsigned short* hs = (unsigned short*)d_ws;  // 4*16384*128 f16-bits = 16.8 MB
    float* out = (float*)d_out;                  // f32, [2][4][16384] flat

    hipLaunchKernelGGL(gru_kernel, dim3(1), dim3(512), 0, stream,
                       px, py, vx, vy, Wemb, bemb, Wih, Whh, bih, bhh,
                       step_mask, ctx, hs);
    hipLaunchKernelGGL(head_kernel, dim3(1024), dim3(64), 0, stream,
                       W1, b1, W2, b2, W3, b3, (const __half*)hs, out);
}

// Round 7
// 7034.225 us; speedup vs baseline: 1.0992x; 1.0123x over previous
//
#include <hip/hip_runtime.h>
#include <hip/hip_fp16.h>

#define TLEN 16384
#define HD 128
#define L2E 1.4426950408889634f

typedef _Float16 v8h __attribute__((ext_vector_type(8)));
typedef float    v4f __attribute__((ext_vector_type(4)));

union U4H8 { uint4 u; v8h h; };

// scaled f32->f16 fragment converters (scale folded at build time, free)
__device__ __forceinline__ v8h cvt8s(const float* p, float sc) {
    v8h r;
    #pragma unroll
    for (int i = 0; i < 8; ++i) r[i] = (_Float16)(p[i] * sc);
    return r;
}
__device__ __forceinline__ v8h cvt8sums(const float* p, const float* q, float sc) {
    v8h r;
    #pragma unroll
    for (int i = 0; i < 8; ++i) r[i] = (_Float16)((p[i] + q[i]) * sc);
    return r;
}
__device__ __forceinline__ unsigned int packh2(float a, float b) {
    union { _Float16 h[2]; unsigned int u; } c;
    c.h[0] = (_Float16)a; c.h[1] = (_Float16)b; return c.u;
}
// compile-time-indexed component select (runtime g, no dynamic extract)
__device__ __forceinline__ float selg(v4f a, int g) {
    const float lo = (g & 1) ? a.y : a.x;
    const float hi = (g & 1) ? a.w : a.z;
    return (g & 2) ? hi : lo;
}
// native transcendentals: v_exp_f32 is exp2; v_rcp_f32 ~1ulp. Avoids the
// IEEE div_scale/div_fmas/div_fixup sequence (~10 VALU each) the compiler
// emits for 1.f/x without fast-math.
__device__ __forceinline__ float fexp2(float x) {
    float r; asm("v_exp_f32 %0, %1" : "=v"(r) : "v"(x)); return r;
}
__device__ __forceinline__ float frcp(float x) {
    float r; asm("v_rcp_f32 %0, %1" : "=v"(r) : "v"(x)); return r;
}
// pin a fragment into the AGPR half of the unified file: relieves the arch
// VGPR budget (need <=~128 arch VGPR for 2 waves/SIMD) AND is remat-proof.
#define PINA(x) asm volatile("" : "+a"(x))

// Raw workgroup barrier: LDS visibility only (lgkmcnt). No vmcnt/expcnt
// drain, so hs global stores stay in flight across steps.
#define BAR() asm volatile("s_waitcnt lgkmcnt(0)\n\ts_barrier" ::: "memory")

// 4-deep K accumulation chain over one 16-row tile (K=128)
__device__ __forceinline__ v4f ch4(v8h a0, v8h a1, v8h a2, v8h a3,
                                   v8h B0, v8h B1, v8h B2, v8h B3, v4f c) {
    c = __builtin_amdgcn_mfma_f32_16x16x32_f16(a0, B0, c, 0, 0, 0);
    c = __builtin_amdgcn_mfma_f32_16x16x32_f16(a1, B1, c, 0, 0, 0);
    c = __builtin_amdgcn_mfma_f32_16x16x32_f16(a2, B2, c, 0, 0, 0);
    return __builtin_amdgcn_mfma_f32_16x16x32_f16(a3, B3, c, 0, 0, 0);
}
// GRU epilogue on PRE-SCALED preacts:
//   sRp = -log2e * sR, sZp = -log2e * sZ, ginp/ghnp = 2*log2e * (gin/ghn)
//   sigmoid(x) = rcp(1 + exp2(-log2e x)); tanh via exp2 of the 2log2e form.
__device__ __forceinline__ float gru_h(float sRp, float sZp, float ginp,
                                       float ghnp, float hold) {
    const float r  = frcp(1.f + fexp2(sRp));
    const float z  = frcp(1.f + fexp2(sZp));
    const float e2 = fexp2(fmaf(r, ghnp, ginp));
    const float n  = fmaf(-2.f, frcp(e2 + 1.f), 1.f);   // tanh
    return fmaf(z, hold - n, n);                        // (1-z)n + z h
}

// ---------------------------------------------------------------------------
// R19 gru = byte-identical to R18/R16 (verified floor: ~6950us).  The step
// loop is register-schedule-critical (R17 lesson) — do not touch.
// Structure: 8 waves (2/SIMD); merged Ws=Wih+Whh r/z gates, split n gate;
// ballot-mask ux branch; lgkm-only raw barrier; fire-and-forget hs stores;
// parity-specialized h2L dbuf (352B c-stride, conflict-free); rcp/exp2
// epilogue with log2e folded into weights; 8-step immediate-offset unroll.
// ---------------------------------------------------------------------------
__global__
__attribute__((amdgpu_flat_work_group_size(512, 512)))
void gru_kernel(
    const float* __restrict__ px,
    const float* __restrict__ py,
    const float* __restrict__ vx,
    const float* __restrict__ vy,
    const float* __restrict__ Wemb,   // [128,4]
    const float* __restrict__ bemb,   // [128]
    const float* __restrict__ Wih,    // [384,128]
    const float* __restrict__ Whh,    // [384,128]
    const float* __restrict__ bih,    // [384]
    const float* __restrict__ bhh,    // [384]
    const int*   __restrict__ step_mask, // [16384]
    const int*   __restrict__ ctxp,      // [1]
    unsigned short* __restrict__ hs)     // [4*16384*128] f16-bits staging
{
    const int tid  = threadIdx.x;       // 0..511
    const int w    = tid >> 6;          // wave 0..7 -> k-range 16w..16w+15
    const int lane = tid & 63;
    const int m    = lane & 15;         // A-frag row within 16-row tile
    const int q8   = (lane >> 4) * 8;   // A/B k-offset within 32-K frag
    const int qq4  = (lane >> 4) * 4;   // D row-block
    const int cme  = lane & 3;          // my chain (D col & B chain)
    const int gme  = (lane >> 2) & 3;   // my row-within-block (replica split)
    const int kme  = 16 * w + qq4 + gme; // my h index

    __shared__ alignas(16) _Float16 h2L[2][4][176];  // dbuf, 352B c-stride
    __shared__ alignas(16) uint4 xpadL[256][4];      // [x0..x3,1,0,0,0] f16
    __shared__ float WembL[512];
    __shared__ float bembL[128];
    __shared__ alignas(16) float Wc4[384][4];
    __shared__ float bfoldL[384];                    // Wih·bemb (no bih)

    // ---- A-fragments: Whh r/z/n, Wih n, merged Ws r/z  (24 frags) ----
    // r,z scaled by -log2e; n by +2log2e (see gru_h).
    v8h ahr0, ahr1, ahr2, ahr3, ahz0, ahz1, ahz2, ahz3, ahn0, ahn1, ahn2, ahn3;
    v8h ain0, ain1, ain2, ain3;
    v8h asr0, asr1, asr2, asr3, asz0, asz1, asz2, asz3;
    {
        const float sRZ = -L2E, sN = 2.f * L2E;
        const float* pr = Whh + (size_t)(      16 * w + m) * 128 + q8;
        const float* pz = Whh + (size_t)(128 + 16 * w + m) * 128 + q8;
        const float* pn = Whh + (size_t)(256 + 16 * w + m) * 128 + q8;
        const float* qr = Wih + (size_t)(      16 * w + m) * 128 + q8;
        const float* qz = Wih + (size_t)(128 + 16 * w + m) * 128 + q8;
        const float* qn = Wih + (size_t)(256 + 16 * w + m) * 128 + q8;
        ahr0 = cvt8s(pr, sRZ); ahr1 = cvt8s(pr + 32, sRZ); ahr2 = cvt8s(pr + 64, sRZ); ahr3 = cvt8s(pr + 96, sRZ);
        ahz0 = cvt8s(pz, sRZ); ahz1 = cvt8s(pz + 32, sRZ); ahz2 = cvt8s(pz + 64, sRZ); ahz3 = cvt8s(pz + 96, sRZ);
        ahn0 = cvt8s(pn, sN);  ahn1 = cvt8s(pn + 32, sN);  ahn2 = cvt8s(pn + 64, sN);  ahn3 = cvt8s(pn + 96, sN);
        ain0 = cvt8s(qn, sN);  ain1 = cvt8s(qn + 32, sN);  ain2 = cvt8s(qn + 64, sN);  ain3 = cvt8s(qn + 96, sN);
        asr0 = cvt8sums(pr, qr, sRZ);           asr1 = cvt8sums(pr + 32, qr + 32, sRZ);
        asr2 = cvt8sums(pr + 64, qr + 64, sRZ); asr3 = cvt8sums(pr + 96, qr + 96, sRZ);
        asz0 = cvt8sums(pz, qz, sRZ);           asz1 = cvt8sums(pz + 32, qz + 32, sRZ);
        asz2 = cvt8sums(pz + 64, qz + 64, sRZ); asz3 = cvt8sums(pz + 96, qz + 96, sRZ);
    }
    PINA(ahr0); PINA(ahr1); PINA(ahr2); PINA(ahr3);
    PINA(ahz0); PINA(ahz1); PINA(ahz2); PINA(ahz3);
    PINA(ahn0); PINA(ahn1); PINA(ahn2); PINA(ahn3);
    PINA(ain0); PINA(ain1); PINA(ain2); PINA(ain3);
    PINA(asr0); PINA(asr1); PINA(asr2); PINA(asr3);
    PINA(asz0); PINA(asz1); PINA(asz2); PINA(asz3);

    // ---- biases as MFMA C-initializers (rows 4q..4q+3), pre-scaled ----
    const int rB = 16 * w + qq4;
    v4f bSR, bSZ, bHN, bIN;
    #pragma unroll
    for (int j = 0; j < 4; ++j) {
        bSR[j] = -L2E * (bih[rB + j]       + bhh[rB + j]);
        bSZ[j] = -L2E * (bih[128 + rB + j] + bhh[128 + rB + j]);
        bHN[j] = 2.f * L2E * bhh[256 + rB + j];
        bIN[j] = 2.f * L2E * bih[256 + rB + j];
    }

    WembL[tid] = Wemb[tid];
    if (tid < 128) bembL[tid] = bemb[tid];
    // zero both h-exchange banks (bank 0 is "h_{-1}" for step 0)
    for (int i = tid; i < 2 * 4 * 176; i += 512) ((_Float16*)h2L)[i] = (_Float16)0.f;
    __syncthreads();
    // folded embed: Wc[g] = Wih[g]·Wemb, bfold[g] = Wih[g]·bemb  (NO bih)
    if (tid < 384) {
        const float* wr = Wih + (size_t)tid * 128;
        float c0 = 0.f, c1 = 0.f, c2 = 0.f, c3 = 0.f, cb = 0.f;
        #pragma unroll 4
        for (int j = 0; j < 128; ++j) {
            const float wv = wr[j];
            const float4 e = *(const float4*)&WembL[j * 4];
            c0 = fmaf(wv, e.x, c0); c1 = fmaf(wv, e.y, c1);
            c2 = fmaf(wv, e.z, c2); c3 = fmaf(wv, e.w, c3);
            cb = fmaf(wv, bembL[j], cb);
        }
        Wc4[tid][0] = c0; Wc4[tid][1] = c1; Wc4[tid][2] = c2; Wc4[tid][3] = c3;
        bfoldL[tid] = cb;
    }
    __syncthreads();
    // Wc A-frags (pre-scaled): k=0..3 = Wc row, k=4 = bemb-fold, rest 0
    v8h wcr = {}, wcz = {}, wcn = {};
    if (lane < 16) {
        const int r0 = 16 * w + m, r1 = 128 + r0, r2 = 256 + r0;
        wcr[0] = (_Float16)(-L2E * Wc4[r0][0]); wcr[1] = (_Float16)(-L2E * Wc4[r0][1]);
        wcr[2] = (_Float16)(-L2E * Wc4[r0][2]); wcr[3] = (_Float16)(-L2E * Wc4[r0][3]);
        wcr[4] = (_Float16)(-L2E * bfoldL[r0]);
        wcz[0] = (_Float16)(-L2E * Wc4[r1][0]); wcz[1] = (_Float16)(-L2E * Wc4[r1][1]);
        wcz[2] = (_Float16)(-L2E * Wc4[r1][2]); wcz[3] = (_Float16)(-L2E * Wc4[r1][3]);
        wcz[4] = (_Float16)(-L2E * bfoldL[r1]);
        wcn[0] = (_Float16)(2.f * L2E * Wc4[r2][0]); wcn[1] = (_Float16)(2.f * L2E * Wc4[r2][1]);
        wcn[2] = (_Float16)(2.f * L2E * Wc4[r2][2]); wcn[3] = (_Float16)(2.f * L2E * Wc4[r2][3]);
        wcn[4] = (_Float16)(2.f * L2E * bfoldL[r2]);
    }
    PINA(wcr); PINA(wcz); PINA(wcn);

    const int ctxm = (ctxp[0] < 1) ? 1 : ctxp[0];
    float hold1 = 0.f;                 // my (cme,kme) h state, f32

    // parity-specialized LDS pointers (even step: read bank0, write bank1)
    const uint4* rdA = (const uint4*)&h2L[0][cme][0] + (lane >> 4);
    const uint4* rdB = (const uint4*)&h2L[1][cme][0] + (lane >> 4);
    _Float16*    wrA = &h2L[1][cme][kme];
    _Float16*    wrB = &h2L[0][cme][kme];
    // per-lane hs stream pointer; advanced once per 8 steps, stores use
    // compile-time immediate offsets (128*i elements = 256*i bytes < 4096)
    unsigned short* hp = hs + (size_t)cme * (TLEN * 128) + kme;

#define STEP(RD, WR, XOFF, HOFF, UX)                                         \
    {                                                                        \
        U4H8 b0, b1, b2, b3;                                                 \
        b0.u = (RD)[0]; b1.u = (RD)[4]; b2.u = (RD)[8]; b3.u = (RD)[12];     \
        v4f aR, aZ, aNi;                                                     \
        v4f aNh = ch4(ahn0, ahn1, ahn2, ahn3, b0.h, b1.h, b2.h, b3.h, bHN);  \
        if (!(UX)) {                                                         \
            aR  = ch4(asr0, asr1, asr2, asr3, b0.h, b1.h, b2.h, b3.h, bSR);  \
            aNi = ch4(ain0, ain1, ain2, ain3, b0.h, b1.h, b2.h, b3.h, bIN);  \
            aZ  = ch4(asz0, asz1, asz2, asz3, b0.h, b1.h, b2.h, b3.h, bSZ);  \
        } else {                                                             \
            U4H8 xb; xb.u = xq[XOFF];                                        \
            aR  = ch4(ahr0, ahr1, ahr2, ahr3, b0.h, b1.h, b2.h, b3.h, bSR);  \
            aR  = __builtin_amdgcn_mfma_f32_16x16x32_f16(wcr, xb.h, aR, 0, 0, 0); \
            aNi = __builtin_amdgcn_mfma_f32_16x16x32_f16(wcn, xb.h, bIN, 0, 0, 0); \
            aZ  = ch4(ahz0, ahz1, ahz2, ahz3, b0.h, b1.h, b2.h, b3.h, bSZ);  \
            aZ  = __builtin_amdgcn_mfma_f32_16x16x32_f16(wcz, xb.h, aZ, 0, 0, 0); \
        }                                                                    \
        const float hnew = gru_h(selg(aR, gme), selg(aZ, gme),               \
                                 selg(aNi, gme), selg(aNh, gme), hold1);     \
        hold1 = hnew;                                                        \
        union { _Float16 f; unsigned short u; } hv; hv.f = (_Float16)hnew;   \
        *(WR) = hv.f;                                                        \
        hp[HOFF] = hv.u;                                                     \
        BAR();                                                               \
    }

    for (int t0 = 0; t0 < TLEN; t0 += 256) {
        // prefetch x (f16-padded with 1.0 at k=4)
        for (int i = tid; i < 1024; i += 512) {
            const int t = i >> 2, c = i & 3;
            const int gt = t0 + t;
            const float* xa = (c == 0) ? px : (c == 1) ? py : (c == 2) ? vx : vy;
            uint4 u;
            u.x = packh2(xa[gt],            xa[TLEN + gt]);
            u.y = packh2(xa[2 * TLEN + gt], xa[3 * TLEN + gt]);
            u.z = packh2(1.f, 0.f);
            u.w = 0u;
            xpadL[t][c] = u;
        }
        // use_x flags for the 256 steps as 4 wave-uniform 64-bit masks
        unsigned long long mb0, mb1, mb2, mb3;
        {
            const int tb = t0 + lane;
            mb0 = __ballot((tb       < ctxm) || (step_mask[tb      ] == 0));
            mb1 = __ballot((tb +  64 < ctxm) || (step_mask[tb +  64] == 0));
            mb2 = __ballot((tb + 128 < ctxm) || (step_mask[tb + 128] == 0));
            mb3 = __ballot((tb + 192 < ctxm) || (step_mask[tb + 192] == 0));
        }
        BAR();
        const uint4* xq = (const uint4*)&xpadL[0][cme];
        #pragma unroll 1
        for (int j = 0; j < 4; ++j) {
            const unsigned long long mj =
                (j == 0) ? mb0 : (j == 1) ? mb1 : (j == 2) ? mb2 : mb3;
            #pragma unroll 1
            for (int t2 = 0; t2 < 64; t2 += 8) {
                const unsigned u0 = (unsigned)(mj >> t2);   // low 8 bits used
                STEP(rdA, wrA,  0,   0, (u0      ) & 1u);
                STEP(rdB, wrB,  4, 128, (u0 >> 1) & 1u);
                STEP(rdA, wrA,  8, 256, (u0 >> 2) & 1u);
                STEP(rdB, wrB, 12, 384, (u0 >> 3) & 1u);
                STEP(rdA, wrA, 16, 512, (u0 >> 4) & 1u);
                STEP(rdB, wrB, 20, 640, (u0 >> 5) & 1u);
                STEP(rdA, wrA, 24, 768, (u0 >> 6) & 1u);
                STEP(rdB, wrB, 28, 896, (u0 >> 7) & 1u);
                xq += 32;
                hp += 1024;
            }
        }
    }
#undef STEP
}

// ---------------------------------------------------------------------------
// Head MLP v2: 256 blocks x 256 threads = exactly 1 block/CU, ONE dispatch
// round (v1: 1024 x 64 at 49KB LDS -> 3 blocks/CU residency cap -> 2 rounds
// + 4x redundant weight loads).  Weights loaded once per CU; y1 staged in
// LDS [256][65] (stride-65: conflict-free).  Total LDS ~117 KB (fits; we
// want exactly 1 block/CU).  Same math, same output layout.
// ---------------------------------------------------------------------------
__global__ __launch_bounds__(256) void head_kernel(
    const float*  __restrict__ W1,
    const float*  __restrict__ b1,
    const float*  __restrict__ W2,
    const float*  __restrict__ b2,
    const float*  __restrict__ W3,
    const float*  __restrict__ b3,
    const __half* __restrict__ hs,
    float*        __restrict__ out)
{
    __shared__ float W1L[64 * 128];     // 32 KB
    __shared__ float W2L[64 * 64];      // 16 KB
    __shared__ float W3L[2 * 64];
    __shared__ float b1L[64], b2L[64], b3L[2];
    __shared__ float y1L[256 * 65];     // 65 KB, stride-65 conflict-free

    const int tid = threadIdx.x;        // 0..255
    {
        float4* dst1 = (float4*)W1L; const float4* src1 = (const float4*)W1;
        for (int i = tid; i < 2048; i += 256) dst1[i] = src1[i];
        float4* dst2 = (float4*)W2L; const float4* src2 = (const float4*)W2;
        for (int i = tid; i < 1024; i += 256) dst2[i] = src2[i];
        if (tid < 32) ((float4*)W3L)[tid] = ((const float4*)W3)[tid];
        if (tid < 64) { b1L[tid] = b1[tid]; b2L[tid] = b2[tid]; }
        if (tid < 2) b3L[tid] = b3[tid];
    }
    __syncthreads();

    const int row = blockIdx.x * 256 + tid;
    float h[128];
    {
        const uint4* hp = (const uint4*)(hs + (size_t)row * HD);
        #pragma unroll
        for (int c = 0; c < 16; ++c) {
            uint4 q = hp[c];
            const __half2* hh = (const __half2*)&q;
            #pragma unroll
            for (int d = 0; d < 4; ++d) {
                const float2 f = __half22float2(hh[d]);
                h[c*8 + d*2 + 0] = f.x;
                h[c*8 + d*2 + 1] = f.y;
            }
        }
    }
    for (int l = 0; l < 64; ++l) {
        float a0 = b1L[l], a1 = 0.f;
        #pragma unroll
        for (int j = 0; j < 128; j += 4) {
            const float4 wv = *(const float4*)&W1L[l*128 + j];
            a0 = fmaf(wv.x, h[j+0], a0);
            a1 = fmaf(wv.y, h[j+1], a1);
            a0 = fmaf(wv.z, h[j+2], a0);
            a1 = fmaf(wv.w, h[j+3], a1);
        }
        const float acc = a0 + a1;
        y1L[tid * 65 + l] = (acc > 0.f) ? acc : (__expf(acc) - 1.f);
    }
    float y30 = b3L[0], y31 = b3L[1];
    for (int l = 0; l < 64; ++l) {
        float a0 = b2L[l], a1 = 0.f;
        const int yb = tid * 65;
        #pragma unroll
        for (int j = 0; j < 64; j += 4) {
            const float4 wv = *(const float4*)&W2L[l*64 + j];
            a0 = fmaf(wv.x, y1L[yb + j+0], a0);
            a1 = fmaf(wv.y, y1L[yb + j+1], a1);
            a0 = fmaf(wv.z, y1L[yb + j+2], a0);
            a1 = fmaf(wv.w, y1L[yb + j+3], a1);
        }
        const float acc = a0 + a1;
        const float v = (acc > 0.f) ? acc : (__expf(acc) - 1.f);
        y30 = fmaf(W3L[l],      v, y30);
        y31 = fmaf(W3L[64 + l], v, y31);
    }
    out[row]            = y30;
    out[4 * TLEN + row] = y31;
}

extern "C" void kernel_launch(void* const* d_in, const int* in_sizes, int n_in,
                              void* d_out, int out_size, void* d_ws, size_t ws_size,
                              hipStream_t stream) {
    const float* px   = (const float*)d_in[0];
    const float* py   = (const float*)d_in[1];
    const float* vx   = (const float*)d_in[2];
    const float* vy   = (const float*)d_in[3];
    const float* Wemb = (const float*)d_in[4];
    const float* bemb = (const float*)d_in[5];
    const float* Wih  = (const float*)d_in[6];
    const float* Whh  = (const float*)d_in[7];
    const float* bih  = (const float*)d_in[8];
    const float* bhh  = (const float*)d_in[9];
    const float* W1   = (const float*)d_in[10];
    const float* b1   = (const float*)d_in[11];
    const float* W2   = (const float*)d_in[12];
    const float* b2   = (const float*)d_in[13];
    const float* W3   = (const float*)d_in[14];
    const float* b3   = (const float*)d_in[15];
    const int* step_mask = (const int*)d_in[16];
    const int* ctx       = (const int*)d_in[17];
    unsigned short* hs = (unsigned short*)d_ws;  // 4*16384*128 f16-bits = 16.8 MB
    float* out = (float*)d_out;                  // f32, [2][4][16384] flat

    hipLaunchKernelGGL(gru_kernel, dim3(1), dim3(512), 0, stream,
                       px, py, vx, vy, Wemb, bemb, Wih, Whh, bih, bhh,
                       step_mask, ctx, hs);
    hipLaunchKernelGGL(head_kernel, dim3(256), dim3(256), 0, stream,
                       W1, b1, W2, b2, W3, b3, (const __half*)hs, out);
}